// Round 5
// baseline (658.553 us; speedup 1.0000x reference)
//
#include <hip/hip_runtime.h>

#define BDIM 32
#define SDIM 512
#define DDIM 1024
#define ADIM 4
#define NCAND 65536

typedef float vfloat4 __attribute__((ext_vector_type(4)));

__global__ __launch_bounds__(256) void cand_repr_kernel(
    const float* __restrict__ word_repr,   // [B,S,D]
    const int*   __restrict__ cand_idx,    // [N,3]
    const int*   __restrict__ anchor_loc,  // [B,S,A,2]
    const int*   __restrict__ anchor_cls,  // [B,S,A]
    float* __restrict__ out_repr,          // [N,D]
    float* __restrict__ out_label,         // [N]
    float* __restrict__ out_counts,        // [B]
    float* __restrict__ out_valid,         // [N]
    float* __restrict__ out_loc)           // [N,2]
{
    const int n   = blockIdx.x;
    const int tid = threadIdx.x;

    // Index chain (block-uniform, broadcast loads).
    const int b = cand_idx[n * 3 + 0];
    const int w = cand_idx[n * 3 + 1];
    const int a = cand_idx[n * 3 + 2];
    const int base = (b * SDIM + w) * ADIM + a;
    const int sid = anchor_loc[base * 2 + 0];
    const int eid = anchor_loc[base * 2 + 1];
    const int len = eid - sid;            // in [0, 8]
    const bool valid = len > 0;

    if (tid == 0) {
        out_label[n]     = valid ? (float)anchor_cls[base] : -1.0f;
        out_valid[n]     = valid ? 1.0f : 0.0f;
        out_loc[n*2 + 0] = valid ? (float)sid : 0.0f;
        out_loc[n*2 + 1] = valid ? (float)eid : 0.0f;
        if (valid) atomicAdd(&out_counts[b], 1.0f);
    }

    // Span mean-pool. Branchless: always issue 8 loads (row clamped into the
    // span so extra loads are same-cacheline L1 hits), keeping 8 requests in
    // flight per wave instead of 1. Weight out-of-span rows by 0.
    const vfloat4* __restrict__ src =
        (const vfloat4*)(word_repr + ((size_t)b * SDIM + sid) * DDIM);
    const int mclamp = (len > 0 ? len : 1) - 1;   // last valid row offset

    vfloat4 v[8];
    #pragma unroll
    for (int s = 0; s < 8; ++s) {
        int r = s < mclamp ? s : mclamp;          // min(s, len-1)
        v[s] = src[(size_t)r * (DDIM / 4) + tid];
    }

    vfloat4 acc = (vfloat4)(0.0f);
    #pragma unroll
    for (int s = 0; s < 8; ++s) {
        float wgt = (s < len) ? 1.0f : 0.0f;
        acc += v[s] * wgt;
    }

    const float scale = valid ? 1.0f / (float)len : 0.0f;
    acc *= scale;

    // Nontemporal: out_repr is a 268MB stream, never re-read. Keep it out of
    // L2/L3 so word_repr stays resident.
    vfloat4* dst = (vfloat4*)(out_repr + (size_t)n * DDIM) + tid;
    __builtin_nontemporal_store(acc, dst);
}

extern "C" void kernel_launch(void* const* d_in, const int* in_sizes, int n_in,
                              void* d_out, int out_size, void* d_ws, size_t ws_size,
                              hipStream_t stream) {
    const float* word_repr  = (const float*)d_in[0];
    const int*   cand_idx   = (const int*)d_in[1];
    const int*   anchor_loc = (const int*)d_in[2];
    const int*   anchor_cls = (const int*)d_in[3];

    float* out = (float*)d_out;
    float* out_repr   = out;                                   // N*D
    float* out_label  = out_repr  + (size_t)NCAND * DDIM;      // N
    float* out_counts = out_label + NCAND;                     // B
    float* out_valid  = out_counts + BDIM;                     // N
    float* out_loc    = out_valid + NCAND;                     // N*2

    (void)hipMemsetAsync(out_counts, 0, BDIM * sizeof(float), stream);
    cand_repr_kernel<<<NCAND, 256, 0, stream>>>(
        word_repr, cand_idx, anchor_loc, anchor_cls,
        out_repr, out_label, out_counts, out_valid, out_loc);
}

// Round 7
// 432.120 us; speedup vs baseline: 1.5240x; 1.5240x over previous
//
#include <hip/hip_runtime.h>

#define BDIM 32
#define SDIM 512
#define DDIM 1024
#define ADIM 4
#define NCAND 65536
#define AUX_BLOCKS 64
#define AUX_THREADS 1024

typedef float vfloat4 __attribute__((ext_vector_type(4)));
typedef float vfloat2 __attribute__((ext_vector_type(2)));

// One block per candidate: mean-pool up to 8 contiguous 4KB rows.
__global__ __launch_bounds__(256) void repr_kernel(
    const float* __restrict__ word_repr,   // [B,S,D]
    const int*   __restrict__ cand_idx,    // [N,3]
    const int*   __restrict__ anchor_loc,  // [B,S,A,2]
    float* __restrict__ out_repr)          // [N,D]
{
    const int n   = blockIdx.x;
    const int tid = threadIdx.x;

    const int b = cand_idx[n * 3 + 0];
    const int w = cand_idx[n * 3 + 1];
    const int a = cand_idx[n * 3 + 2];
    const int base = (b * SDIM + w) * ADIM + a;
    const int sid = anchor_loc[base * 2 + 0];
    const int eid = anchor_loc[base * 2 + 1];
    const int len = eid - sid;            // in [0, 8]

    // Branchless 8-deep load pipeline; rows clamped into the span so the
    // extra loads are L1 same-line hits. sched_barrier keeps all 8 loads
    // issued before any accumulate -> 8 outstanding requests per wave.
    const vfloat4* __restrict__ src =
        (const vfloat4*)(word_repr + ((size_t)b * SDIM + sid) * DDIM);
    const int mclamp = (len > 0 ? len : 1) - 1;

    vfloat4 v[8];
    #pragma unroll
    for (int s = 0; s < 8; ++s) {
        int r = s < mclamp ? s : mclamp;
        v[s] = src[(size_t)r * (DDIM / 4) + tid];
    }
    __builtin_amdgcn_sched_barrier(0);

    vfloat4 acc = (vfloat4)(0.0f);
    #pragma unroll
    for (int s = 0; s < 8; ++s) {
        float wgt = (s < len) ? 1.0f : 0.0f;
        acc += v[s] * wgt;
    }
    const float scale = (len > 0) ? 1.0f / (float)len : 0.0f;
    acc *= scale;

    vfloat4* dst = (vfloat4*)(out_repr + (size_t)n * DDIM) + tid;
    __builtin_nontemporal_store(acc, dst);
}

// One thread per candidate: label/valid/loc + LDS count histogram -> partials.
// NO global atomics (same-cacheline atomic serialization was the round-1/5
// bottleneck theory: 65536 atomics onto 2 lines ~= 1M cycles ~= the whole 414us).
__global__ __launch_bounds__(AUX_THREADS) void aux_kernel(
    const int* __restrict__ cand_idx,     // [N,3]
    const int* __restrict__ anchor_loc,   // [B,S,A,2]
    const int* __restrict__ anchor_cls,   // [B,S,A]
    float* __restrict__ out_label,        // [N]
    float* __restrict__ out_valid,        // [N]
    float* __restrict__ out_loc,          // [N,2]
    float* __restrict__ partial)          // [AUX_BLOCKS, BDIM] in d_ws
{
    __shared__ int hist[BDIM];
    const int tid = threadIdx.x;
    if (tid < BDIM) hist[tid] = 0;
    __syncthreads();

    const int n = blockIdx.x * AUX_THREADS + tid;
    const int b = cand_idx[n * 3 + 0];
    const int w = cand_idx[n * 3 + 1];
    const int a = cand_idx[n * 3 + 2];
    const int base = (b * SDIM + w) * ADIM + a;
    const int sid = anchor_loc[base * 2 + 0];
    const int eid = anchor_loc[base * 2 + 1];
    const bool valid = eid > sid;

    out_label[n] = valid ? (float)anchor_cls[base] : -1.0f;
    out_valid[n] = valid ? 1.0f : 0.0f;
    vfloat2 lc;
    lc.x = valid ? (float)sid : 0.0f;
    lc.y = valid ? (float)eid : 0.0f;
    *(vfloat2*)(out_loc + (size_t)n * 2) = lc;

    if (valid) atomicAdd(&hist[b], 1);   // LDS atomic: cheap
    __syncthreads();
    if (tid < BDIM) partial[blockIdx.x * BDIM + tid] = (float)hist[tid];
}

__global__ void count_reduce_kernel(const float* __restrict__ partial,
                                    float* __restrict__ out_counts)
{
    const int b = threadIdx.x;            // 32 threads
    if (b < BDIM) {
        float s = 0.0f;
        for (int i = 0; i < AUX_BLOCKS; ++i) s += partial[i * BDIM + b];
        out_counts[b] = s;
    }
}

extern "C" void kernel_launch(void* const* d_in, const int* in_sizes, int n_in,
                              void* d_out, int out_size, void* d_ws, size_t ws_size,
                              hipStream_t stream) {
    const float* word_repr  = (const float*)d_in[0];
    const int*   cand_idx   = (const int*)d_in[1];
    const int*   anchor_loc = (const int*)d_in[2];
    const int*   anchor_cls = (const int*)d_in[3];

    float* out = (float*)d_out;
    float* out_repr   = out;                                   // N*D
    float* out_label  = out_repr  + (size_t)NCAND * DDIM;      // N
    float* out_counts = out_label + NCAND;                     // B
    float* out_valid  = out_counts + BDIM;                     // N
    float* out_loc    = out_valid + NCAND;                     // N*2

    float* partial = (float*)d_ws;                             // AUX_BLOCKS*BDIM

    aux_kernel<<<AUX_BLOCKS, AUX_THREADS, 0, stream>>>(
        cand_idx, anchor_loc, anchor_cls,
        out_label, out_valid, out_loc, partial);
    count_reduce_kernel<<<1, 64, 0, stream>>>(partial, out_counts);
    repr_kernel<<<NCAND, 256, 0, stream>>>(
        word_repr, cand_idx, anchor_loc, out_repr);
}

// Round 8
// 376.564 us; speedup vs baseline: 1.7488x; 1.1475x over previous
//
#include <hip/hip_runtime.h>

#define BDIM 32
#define SDIM 512
#define DDIM 1024
#define ADIM 4
#define NCAND 65536
#define AUX_BLOCKS 64
#define AUX_THREADS 1024
#define BUCKET_SLOTS 4096                 // slack per b (true max ~2200)
#define NSLOTS (BDIM * BUCKET_SLOTS)      // 131072

typedef float vfloat4 __attribute__((ext_vector_type(4)));
typedef float vfloat2 __attribute__((ext_vector_type(2)));

__global__ void init_cursor_kernel(int* cursor) {
    int i = threadIdx.x;
    if (i < BDIM) cursor[i] = i * BUCKET_SLOTS;
}

// One thread per candidate: aux outputs + per-b count partials + counting-sort
// scatter of candidate ids into b-buckets (perm). No hot global atomics:
// LDS ranks + 32 cursor atomics per block (64*32 total).
__global__ __launch_bounds__(AUX_THREADS) void aux_kernel(
    const int* __restrict__ cand_idx,     // [N,3]
    const int* __restrict__ anchor_loc,   // [B,S,A,2]
    const int* __restrict__ anchor_cls,   // [B,S,A]
    float* __restrict__ out_label,        // [N]
    float* __restrict__ out_valid,        // [N]
    float* __restrict__ out_loc,          // [N,2]
    float* __restrict__ partial,          // [AUX_BLOCKS, BDIM]
    int*   __restrict__ cursor,           // [BDIM]
    int*   __restrict__ perm)             // [NSLOTS]
{
    __shared__ int rankh[BDIM];           // all candidates (bucket ranks)
    __shared__ int vhist[BDIM];           // valid-only (counts output)
    __shared__ int baseh[BDIM];
    const int tid = threadIdx.x;
    if (tid < BDIM) { rankh[tid] = 0; vhist[tid] = 0; }
    __syncthreads();

    const int n = blockIdx.x * AUX_THREADS + tid;
    const int b = cand_idx[n * 3 + 0];
    const int w = cand_idx[n * 3 + 1];
    const int a = cand_idx[n * 3 + 2];
    const int base = (b * SDIM + w) * ADIM + a;
    const int sid = anchor_loc[base * 2 + 0];
    const int eid = anchor_loc[base * 2 + 1];
    const bool valid = eid > sid;

    const int r = atomicAdd(&rankh[b], 1);        // LDS: cheap
    if (valid) atomicAdd(&vhist[b], 1);

    out_label[n] = valid ? (float)anchor_cls[base] : -1.0f;
    out_valid[n] = valid ? 1.0f : 0.0f;
    vfloat2 lc;
    lc.x = valid ? (float)sid : 0.0f;
    lc.y = valid ? (float)eid : 0.0f;
    *(vfloat2*)(out_loc + (size_t)n * 2) = lc;

    __syncthreads();
    if (tid < BDIM) {
        baseh[tid] = atomicAdd(&cursor[tid], rankh[tid]);  // 32/block
        partial[blockIdx.x * BDIM + tid] = (float)vhist[tid];
    }
    __syncthreads();
    perm[baseh[b] + r] = n;
}

__global__ void count_reduce_kernel(const float* __restrict__ partial,
                                    float* __restrict__ out_counts)
{
    const int b = threadIdx.x;            // 32 active
    if (b < BDIM) {
        float s = 0.0f;
        for (int i = 0; i < AUX_BLOCKS; ++i) s += partial[i * BDIM + b];
        out_counts[b] = s;
    }
}

// One block per bucket slot, processed in b-sorted order so concurrently
// resident blocks share one 2MB word_repr slice -> L2-resident re-reads.
__global__ __launch_bounds__(256) void repr_kernel(
    const float* __restrict__ word_repr,   // [B,S,D]
    const int*   __restrict__ cand_idx,    // [N,3]
    const int*   __restrict__ anchor_loc,  // [B,S,A,2]
    const int*   __restrict__ perm,        // [NSLOTS], -1 = empty
    float* __restrict__ out_repr)          // [N,D]
{
    const int n = perm[blockIdx.x];
    if (n < 0) return;
    const int tid = threadIdx.x;

    const int b = cand_idx[n * 3 + 0];
    const int w = cand_idx[n * 3 + 1];
    const int a = cand_idx[n * 3 + 2];
    const int base = (b * SDIM + w) * ADIM + a;
    const int sid = anchor_loc[base * 2 + 0];
    const int eid = anchor_loc[base * 2 + 1];
    const int len = eid - sid;            // in [0, 8]

    const vfloat4* __restrict__ src =
        (const vfloat4*)(word_repr + ((size_t)b * SDIM + sid) * DDIM);
    const int mclamp = (len > 0 ? len : 1) - 1;

    vfloat4 v[8];
    #pragma unroll
    for (int s = 0; s < 8; ++s) {
        int r = s < mclamp ? s : mclamp;
        v[s] = src[(size_t)r * (DDIM / 4) + tid];
    }
    __builtin_amdgcn_sched_barrier(0);

    vfloat4 acc = (vfloat4)(0.0f);
    #pragma unroll
    for (int s = 0; s < 8; ++s) {
        float wgt = (s < len) ? 1.0f : 0.0f;
        acc += v[s] * wgt;
    }
    const float scale = (len > 0) ? 1.0f / (float)len : 0.0f;
    acc *= scale;

    vfloat4* dst = (vfloat4*)(out_repr + (size_t)n * DDIM) + tid;
    __builtin_nontemporal_store(acc, dst);
}

extern "C" void kernel_launch(void* const* d_in, const int* in_sizes, int n_in,
                              void* d_out, int out_size, void* d_ws, size_t ws_size,
                              hipStream_t stream) {
    const float* word_repr  = (const float*)d_in[0];
    const int*   cand_idx   = (const int*)d_in[1];
    const int*   anchor_loc = (const int*)d_in[2];
    const int*   anchor_cls = (const int*)d_in[3];

    float* out = (float*)d_out;
    float* out_repr   = out;                                   // N*D
    float* out_label  = out_repr  + (size_t)NCAND * DDIM;      // N
    float* out_counts = out_label + NCAND;                     // B
    float* out_valid  = out_counts + BDIM;                     // N
    float* out_loc    = out_valid + NCAND;                     // N*2

    float* partial = (float*)d_ws;                             // 64*32 floats
    int*   cursor  = (int*)(partial + AUX_BLOCKS * BDIM);      // 32 ints
    int*   perm    = cursor + BDIM;                            // NSLOTS ints

    (void)hipMemsetAsync(perm, 0xFF, NSLOTS * sizeof(int), stream);  // -1
    init_cursor_kernel<<<1, 64, 0, stream>>>(cursor);
    aux_kernel<<<AUX_BLOCKS, AUX_THREADS, 0, stream>>>(
        cand_idx, anchor_loc, anchor_cls,
        out_label, out_valid, out_loc, partial, cursor, perm);
    count_reduce_kernel<<<1, 64, 0, stream>>>(partial, out_counts);
    repr_kernel<<<NSLOTS, 256, 0, stream>>>(
        word_repr, cand_idx, anchor_loc, perm, out_repr);
}